// Round 2
// baseline (455.605 us; speedup 1.0000x reference)
//
#include <hip/hip_runtime.h>
#include <hip/hip_bf16.h>

// Problem constants (fixed by setup_inputs): fp32 inputs/outputs.
constexpr int Bn = 4;
constexpr int Tn = 4096;
constexpr int Dn = 256;
constexpr int NT = Tn / 64;            // 64 t-tiles per batch
constexpr int NTRI = NT * (NT + 1) / 2; // 2080 lower-tri 64x64 tiles per batch

using ushort = unsigned short;
typedef short short8 __attribute__((ext_vector_type(8)));
typedef float f32x4 __attribute__((ext_vector_type(4)));

__device__ __forceinline__ ushort f2bu(float f) {
    __hip_bfloat16 h = __float2bfloat16(f);
    return __builtin_bit_cast(unsigned short, h);
}
__device__ __forceinline__ void gld_lds16(const ushort* g, ushort* l) {
    __builtin_amdgcn_global_load_lds((const __attribute__((address_space(1))) void*)g,
                                     (__attribute__((address_space(3))) void*)l,
                                     16, 0, 0);
}

// ---------------- Kernel 1: rowsum -> dis, + write packed-triangular bf16 A ----------------
// One block per row (b,t). Reads 4096 fp32, computes dis = rsqrt(sum+eps) exactly in fp32,
// and stores bf16(A[t, s]) for s-tiles kt <= it into packed tri layout, diag tile pre-masked.
__global__ __launch_bounds__(256) void rowsum_convert_kernel(
    const float* __restrict__ A, float* __restrict__ dis, ushort* __restrict__ Apk) {
    int r = blockIdx.x;                 // b*Tn + t
    int b = r >> 12;
    int t = r & (Tn - 1);
    int it = t >> 6, m = t & 63;
    const float* row = A + (size_t)r * Tn;
    ushort* tb = Apk + (size_t)b * NTRI * 4096 + (size_t)(it * (it + 1) / 2) * 4096 + m * 64;
    int tid = threadIdx.x;
    float s = 0.f;
#pragma unroll
    for (int q = 0; q < 2; ++q) {
        int g = q * 256 + tid;          // group of 8 floats; 512 groups cover the row
        int c0 = g * 8;
        float4 v0 = *(const float4*)(row + c0);
        float4 v1 = *(const float4*)(row + c0 + 4);
        s += v0.x + v0.y + v0.z + v0.w + v1.x + v1.y + v1.z + v1.w;
        int kt = g >> 3;                // which 64-col s-tile
        if (kt <= it) {
            float f[8] = {v0.x, v0.y, v0.z, v0.w, v1.x, v1.y, v1.z, v1.w};
            int c = c0 & 63;
            if (kt == it) {
#pragma unroll
                for (int j = 0; j < 8; ++j)
                    if (c + j > m) f[j] = 0.f;   // causal mask on diagonal tile
            }
            unsigned w[4];
#pragma unroll
            for (int e = 0; e < 4; ++e)
                w[e] = (unsigned)f2bu(f[2 * e]) | ((unsigned)f2bu(f[2 * e + 1]) << 16);
            *(uint4*)(tb + (size_t)kt * 4096 + c) = make_uint4(w[0], w[1], w[2], w[3]);
        }
    }
#pragma unroll
    for (int k = 1; k < 64; k <<= 1) s += __shfl_xor(s, k, 64);
    __shared__ float ws[4];
    if ((tid & 63) == 0) ws[tid >> 6] = s;
    __syncthreads();
    if (tid == 0) {
        float tot = ws[0] + ws[1] + ws[2] + ws[3];
        dis[r] = rsqrtf(tot + 1e-6f);
    }
}

// ---------------- Kernel 2: kT[b][d][s] = bf16(dis[b,s] * k[b][s][d]) ----------------
__global__ __launch_bounds__(256) void scale_transpose_kernel(
    const float* __restrict__ K, const float* __restrict__ dis, ushort* __restrict__ kT) {
    int bid = blockIdx.x;
    int b = bid >> 8;
    int rr = bid & 255;
    int st = rr >> 2, dt = rr & 3;
    int s0 = st * 64, d0 = dt * 64;
    __shared__ ushort tile[64][72];     // padded
    int tid = threadIdx.x;
#pragma unroll
    for (int q = 0; q < 2; ++q) {
        int idx = q * 256 + tid;
        int sl = idx >> 3, dl0 = (idx & 7) * 8;
        const float* g = K + ((size_t)(b * Tn + s0 + sl) * Dn + d0 + dl0);
        float sc = dis[b * Tn + s0 + sl];
        float4 v0 = *(const float4*)g;
        float4 v1 = *(const float4*)(g + 4);
        tile[sl][dl0 + 0] = f2bu(v0.x * sc);
        tile[sl][dl0 + 1] = f2bu(v0.y * sc);
        tile[sl][dl0 + 2] = f2bu(v0.z * sc);
        tile[sl][dl0 + 3] = f2bu(v0.w * sc);
        tile[sl][dl0 + 4] = f2bu(v1.x * sc);
        tile[sl][dl0 + 5] = f2bu(v1.y * sc);
        tile[sl][dl0 + 6] = f2bu(v1.z * sc);
        tile[sl][dl0 + 7] = f2bu(v1.w * sc);
    }
    __syncthreads();
#pragma unroll
    for (int q = 0; q < 2; ++q) {
        int idx = q * 256 + tid;
        int dl = idx >> 3, sl0 = (idx & 7) * 8;
        unsigned w[4];
#pragma unroll
        for (int e = 0; e < 4; ++e) {
            unsigned lo = tile[sl0 + 2 * e][dl];
            unsigned hi = tile[sl0 + 2 * e + 1][dl];
            w[e] = lo | (hi << 16);
        }
        *(uint4*)(kT + ((size_t)(b * Dn + d0 + dl) * Tn + s0 + sl0)) =
            make_uint4(w[0], w[1], w[2], w[3]);
    }
}

// ---------------- Kernel 3: causal MFMA GEMM ----------------
// out[b,t,d] = sqrt(0.5)*dis[t] * sum_{s<=t} Apk[b,t,s] * kT[b,d,s]   (fp32 out)
constexpr int BM = 64, BN = 128, BK = 64;

__global__ __launch_bounds__(256) void gemm_causal_kernel(
    const ushort* __restrict__ Apk, const ushort* __restrict__ kT,
    const float* __restrict__ dis, float* __restrict__ out) {
    __shared__ __attribute__((aligned(16))) ushort As[BM * BK];
    __shared__ __attribute__((aligned(16))) ushort Bs[BN * BK];
    __shared__ float rs[BM];

    int bid = blockIdx.x;
    int it = 63 - (bid >> 3);           // longest-K tiles dispatched first (LPT)
    int sub = bid & 7;
    int b = sub >> 1;
    int d0 = (sub & 1) * BN;
    int t0 = it * BM;

    int tid = threadIdx.x;
    int lane = tid & 63;
    int w = tid >> 6;
    int l15 = lane & 15;
    int kq = (lane >> 4) * 8;

    const ushort* Atri = Apk + (size_t)b * NTRI * 4096 + (size_t)(it * (it + 1) / 2) * 4096;
    const size_t kTbase = (size_t)(b * Dn + d0) * Tn;

    if (tid < BM) rs[tid] = 0.70710678118654752f * dis[b * Tn + t0 + tid];

    f32x4 acc[2][4];
#pragma unroll
    for (int mi = 0; mi < 2; ++mi)
#pragma unroll
        for (int ni = 0; ni < 4; ++ni) acc[mi][ni] = (f32x4){0.f, 0.f, 0.f, 0.f};

    int mrow = (w >> 1) * 32;
    int ncol = (w & 1) * 64;

    int nkt = it + 1;
    for (int kt = 0; kt < nkt; ++kt) {
        // A tile: packed contiguous 8KB (pre-masked diag) -> direct to LDS
#pragma unroll
        for (int q = 0; q < 2; ++q) {
            int idx = q * 256 + tid;
            gld_lds16(Atri + (size_t)kt * 4096 + idx * 8, As + idx * 8);
        }
        int s0 = kt * BK;
        // B tile (kT): 128 rows x 64 cols bf16
#pragma unroll
        for (int q = 0; q < 4; ++q) {
            int idx = q * 256 + tid;
            int n = idx >> 3, sc = (idx & 7) * 8;
            gld_lds16(kT + kTbase + (size_t)n * Tn + s0 + sc, Bs + idx * 8);
        }
        __syncthreads();

#pragma unroll
        for (int ki = 0; ki < 2; ++ki) {
            int kc = ki * 32 + kq;
            short8 af[2];
#pragma unroll
            for (int mi = 0; mi < 2; ++mi)
                af[mi] = *(const short8*)&As[(mrow + 16 * mi + l15) * BK + kc];
            short8 bfr[4];
#pragma unroll
            for (int ni = 0; ni < 4; ++ni)
                bfr[ni] = *(const short8*)&Bs[(ncol + 16 * ni + l15) * BK + kc];
#pragma unroll
            for (int mi = 0; mi < 2; ++mi)
#pragma unroll
                for (int ni = 0; ni < 4; ++ni)
                    acc[mi][ni] = __builtin_amdgcn_mfma_f32_16x16x32_bf16(
                        af[mi], bfr[ni], acc[mi][ni], 0, 0, 0);
        }
        __syncthreads();
    }

    // epilogue: scale by sqrt(gamma)*dis[t], store fp32
#pragma unroll
    for (int mi = 0; mi < 2; ++mi) {
#pragma unroll
        for (int ni = 0; ni < 4; ++ni) {
            int tl = mrow + 16 * mi + (lane >> 4) * 4;
            int d = d0 + ncol + 16 * ni + l15;
#pragma unroll
            for (int r = 0; r < 4; ++r) {
                int t = t0 + tl + r;
                out[(size_t)(b * Tn + t) * Dn + d] = acc[mi][ni][r] * rs[tl + r];
            }
        }
    }
}

extern "C" void kernel_launch(void* const* d_in, const int* in_sizes, int n_in,
                              void* d_out, int out_size, void* d_ws, size_t ws_size,
                              hipStream_t stream) {
    const float* A = (const float*)d_in[0];     // A_rel fp32, (4,4096,4096)
    const float* K = (const float*)d_in[1];     // k_seq fp32, (4,4096,256)
    float* out = (float*)d_out;                 // fp32, (4,4096,256)

    float* dis = (float*)d_ws;                          // 16384 f32 = 64 KB
    ushort* kT = (ushort*)(dis + Bn * Tn);              // 8.39 MB bf16
    ushort* Apk = kT + (size_t)Bn * Dn * Tn;            // 68.2 MB packed-tri bf16

    rowsum_convert_kernel<<<dim3(Bn * Tn), dim3(256), 0, stream>>>(A, dis, Apk);
    scale_transpose_kernel<<<dim3(Bn * (Tn / 64) * (Dn / 64)), dim3(256), 0, stream>>>(K, dis, kT);
    gemm_causal_kernel<<<dim3(NT * 2 * Bn), dim3(256), 0, stream>>>(Apk, kT, dis, out);
}

// Round 3
// 448.790 us; speedup vs baseline: 1.0152x; 1.0152x over previous
//
#include <hip/hip_runtime.h>
#include <hip/hip_bf16.h>

// Problem constants (fixed by setup_inputs): fp32 inputs/outputs.
constexpr int Bn = 4;
constexpr int Tn = 4096;
constexpr int Dn = 256;
constexpr int NT = Tn / 64;             // 64 t-tiles per batch
constexpr int NTRI = NT * (NT + 1) / 2; // 2080 lower-tri 64x64 tiles per batch

using ushort = unsigned short;
typedef short short8 __attribute__((ext_vector_type(8)));
typedef float f32x4 __attribute__((ext_vector_type(4)));

__device__ __forceinline__ ushort f2bu(float f) {
    __hip_bfloat16 h = __float2bfloat16(f);
    return __builtin_bit_cast(unsigned short, h);
}
__device__ __forceinline__ void gld_lds16(const ushort* g, ushort* l) {
    __builtin_amdgcn_global_load_lds((const __attribute__((address_space(1))) void*)g,
                                     (__attribute__((address_space(3))) void*)l,
                                     16, 0, 0);
}

// ---------------- Kernel 1: rowsum -> dis, + write packed-triangular bf16 A ----------------
__global__ __launch_bounds__(256) void rowsum_convert_kernel(
    const float* __restrict__ A, float* __restrict__ dis, ushort* __restrict__ Apk) {
    int r = blockIdx.x;                 // b*Tn + t
    int b = r >> 12;
    int t = r & (Tn - 1);
    int it = t >> 6, m = t & 63;
    const float* row = A + (size_t)r * Tn;
    ushort* tb = Apk + (size_t)b * NTRI * 4096 + (size_t)(it * (it + 1) / 2) * 4096 + m * 64;
    int tid = threadIdx.x;
    float s = 0.f;
#pragma unroll
    for (int q = 0; q < 2; ++q) {
        int g = q * 256 + tid;          // group of 8 floats; 512 groups cover the row
        int c0 = g * 8;
        float4 v0 = *(const float4*)(row + c0);
        float4 v1 = *(const float4*)(row + c0 + 4);
        s += v0.x + v0.y + v0.z + v0.w + v1.x + v1.y + v1.z + v1.w;
        int kt = g >> 3;                // which 64-col s-tile
        if (kt <= it) {
            float f[8] = {v0.x, v0.y, v0.z, v0.w, v1.x, v1.y, v1.z, v1.w};
            int c = c0 & 63;
            if (kt == it) {
#pragma unroll
                for (int j = 0; j < 8; ++j)
                    if (c + j > m) f[j] = 0.f;   // causal mask on diagonal tile
            }
            unsigned w[4];
#pragma unroll
            for (int e = 0; e < 4; ++e)
                w[e] = (unsigned)f2bu(f[2 * e]) | ((unsigned)f2bu(f[2 * e + 1]) << 16);
            *(uint4*)(tb + (size_t)kt * 4096 + c) = make_uint4(w[0], w[1], w[2], w[3]);
        }
    }
#pragma unroll
    for (int k = 1; k < 64; k <<= 1) s += __shfl_xor(s, k, 64);
    __shared__ float ws[4];
    if ((tid & 63) == 0) ws[tid >> 6] = s;
    __syncthreads();
    if (tid == 0) {
        float tot = ws[0] + ws[1] + ws[2] + ws[3];
        dis[r] = rsqrtf(tot + 1e-6f);
    }
}

// ---------------- Kernel 2: kT[b][d][s] = bf16(dis[b,s] * k[b][s][d]) ----------------
__global__ __launch_bounds__(256) void scale_transpose_kernel(
    const float* __restrict__ K, const float* __restrict__ dis, ushort* __restrict__ kT) {
    int bid = blockIdx.x;
    int b = bid >> 8;
    int rr = bid & 255;
    int st = rr >> 2, dt = rr & 3;
    int s0 = st * 64, d0 = dt * 64;
    __shared__ ushort tile[64][72];     // padded
    int tid = threadIdx.x;
#pragma unroll
    for (int q = 0; q < 2; ++q) {
        int idx = q * 256 + tid;
        int sl = idx >> 3, dl0 = (idx & 7) * 8;
        const float* g = K + ((size_t)(b * Tn + s0 + sl) * Dn + d0 + dl0);
        float sc = dis[b * Tn + s0 + sl];
        float4 v0 = *(const float4*)g;
        float4 v1 = *(const float4*)(g + 4);
        tile[sl][dl0 + 0] = f2bu(v0.x * sc);
        tile[sl][dl0 + 1] = f2bu(v0.y * sc);
        tile[sl][dl0 + 2] = f2bu(v0.z * sc);
        tile[sl][dl0 + 3] = f2bu(v0.w * sc);
        tile[sl][dl0 + 4] = f2bu(v1.x * sc);
        tile[sl][dl0 + 5] = f2bu(v1.y * sc);
        tile[sl][dl0 + 6] = f2bu(v1.z * sc);
        tile[sl][dl0 + 7] = f2bu(v1.w * sc);
    }
    __syncthreads();
#pragma unroll
    for (int q = 0; q < 2; ++q) {
        int idx = q * 256 + tid;
        int dl = idx >> 3, sl0 = (idx & 7) * 8;
        unsigned w[4];
#pragma unroll
        for (int e = 0; e < 4; ++e) {
            unsigned lo = tile[sl0 + 2 * e][dl];
            unsigned hi = tile[sl0 + 2 * e + 1][dl];
            w[e] = lo | (hi << 16);
        }
        *(uint4*)(kT + ((size_t)(b * Dn + d0 + dl) * Tn + s0 + sl0)) =
            make_uint4(w[0], w[1], w[2], w[3]);
    }
}

// ---------------- Kernel 3: causal MFMA GEMM, double-buffered ----------------
// out[b,t,d] = sqrt(0.5)*dis[t] * sum_{s<=t} Apk[b,t,s] * kT[b,d,s]   (fp32 out)
// BM=64 x BN=64 tile, BK=64, 2-deep LDS pipeline, 1024 blocks (4/CU), LPT order.
constexpr int BK = 64;

__global__ __launch_bounds__(256) void gemm_causal_kernel(
    const ushort* __restrict__ Apk, const ushort* __restrict__ kT,
    const float* __restrict__ dis, float* __restrict__ out) {
    __shared__ __attribute__((aligned(16))) ushort As[2][64 * BK];
    __shared__ __attribute__((aligned(16))) ushort Bs[2][64 * BK];
    __shared__ float rs[64];

    int bid = blockIdx.x;
    int it = 63 - (bid >> 4);           // longest-K tiles dispatched first (LPT)
    int sub = bid & 15;
    int b = sub >> 2;
    int d0 = (sub & 3) * 64;
    int t0 = it * 64;

    int tid = threadIdx.x;
    int lane = tid & 63;
    int w = tid >> 6;
    int l15 = lane & 15;
    int kq = (lane >> 4) * 8;

    const ushort* Atri = Apk + (size_t)b * NTRI * 4096 + (size_t)(it * (it + 1) / 2) * 4096;
    const size_t kTbase = (size_t)(b * Dn + d0) * Tn;

    if (tid < 64) rs[tid] = 0.70710678118654752f * dis[b * Tn + t0 + tid];

    f32x4 acc[2][2];
#pragma unroll
    for (int mi = 0; mi < 2; ++mi)
#pragma unroll
        for (int ni = 0; ni < 2; ++ni) acc[mi][ni] = (f32x4){0.f, 0.f, 0.f, 0.f};

    int mrow = (w >> 1) * 32;
    int ncol = (w & 1) * 32;
    int nkt = it + 1;

    // stage k-tile `kt` into buffer `buf`
    auto stage = [&](int buf, int kt) {
#pragma unroll
        for (int q = 0; q < 2; ++q) {
            int idx = q * 256 + tid;
            gld_lds16(Atri + (size_t)kt * 4096 + idx * 8, &As[buf][idx * 8]);
        }
#pragma unroll
        for (int q = 0; q < 2; ++q) {
            int idx = q * 256 + tid;
            int n = idx >> 3, sc = (idx & 7) * 8;
            gld_lds16(kT + kTbase + (size_t)n * Tn + kt * BK + sc, &Bs[buf][idx * 8]);
        }
    };

    stage(0, 0);
    __syncthreads();                    // drains vmcnt: buf0 ready

    for (int kt = 0; kt < nkt; ++kt) {
        int cur = kt & 1;
        if (kt + 1 < nkt) stage(cur ^ 1, kt + 1);   // prefetch next tile
#pragma unroll
        for (int ki = 0; ki < 2; ++ki) {
            int kc = ki * 32 + kq;
            short8 af[2];
#pragma unroll
            for (int mi = 0; mi < 2; ++mi)
                af[mi] = *(const short8*)&As[cur][(mrow + 16 * mi + l15) * BK + kc];
            short8 bfr[2];
#pragma unroll
            for (int ni = 0; ni < 2; ++ni)
                bfr[ni] = *(const short8*)&Bs[cur][(ncol + 16 * ni + l15) * BK + kc];
#pragma unroll
            for (int mi = 0; mi < 2; ++mi)
#pragma unroll
                for (int ni = 0; ni < 2; ++ni)
                    acc[mi][ni] = __builtin_amdgcn_mfma_f32_16x16x32_bf16(
                        af[mi], bfr[ni], acc[mi][ni], 0, 0, 0);
        }
        __syncthreads();                // next buffer staged; cur free for overwrite
    }

    // epilogue: scale by sqrt(gamma)*dis[t], store fp32
#pragma unroll
    for (int mi = 0; mi < 2; ++mi) {
#pragma unroll
        for (int ni = 0; ni < 2; ++ni) {
            int tl = mrow + 16 * mi + (lane >> 4) * 4;
            int d = d0 + ncol + 16 * ni + l15;
#pragma unroll
            for (int r = 0; r < 4; ++r) {
                int t = t0 + tl + r;
                out[(size_t)(b * Tn + t) * Dn + d] = acc[mi][ni][r] * rs[tl + r];
            }
        }
    }
}

extern "C" void kernel_launch(void* const* d_in, const int* in_sizes, int n_in,
                              void* d_out, int out_size, void* d_ws, size_t ws_size,
                              hipStream_t stream) {
    const float* A = (const float*)d_in[0];     // A_rel fp32, (4,4096,4096)
    const float* K = (const float*)d_in[1];     // k_seq fp32, (4,4096,256)
    float* out = (float*)d_out;                 // fp32, (4,4096,256)

    float* dis = (float*)d_ws;                          // 16384 f32 = 64 KB
    ushort* kT = (ushort*)(dis + Bn * Tn);              // 8.39 MB bf16
    ushort* Apk = kT + (size_t)Bn * Dn * Tn;            // 68.2 MB packed-tri bf16

    rowsum_convert_kernel<<<dim3(Bn * Tn), dim3(256), 0, stream>>>(A, dis, Apk);
    scale_transpose_kernel<<<dim3(Bn * (Tn / 64) * (Dn / 64)), dim3(256), 0, stream>>>(K, dis, kT);
    gemm_causal_kernel<<<dim3(NT * 16), dim3(256), 0, stream>>>(Apk, kT, dis, out);
}

// Round 4
// 401.773 us; speedup vs baseline: 1.1340x; 1.1170x over previous
//
#include <hip/hip_runtime.h>
#include <hip/hip_bf16.h>

// Problem constants (fixed by setup_inputs): fp32 inputs/outputs.
constexpr int Bn = 4;
constexpr int Tn = 4096;
constexpr int Dn = 256;
constexpr int NT = Tn / 64;             // 64 t-tiles per batch
constexpr int NTRI = NT * (NT + 1) / 2; // 2080 lower-tri 64x64 tiles per batch

using ushort = unsigned short;
typedef short short8 __attribute__((ext_vector_type(8)));
typedef float f32x4 __attribute__((ext_vector_type(4)));

__device__ __forceinline__ ushort f2bu(float f) {
    __hip_bfloat16 h = __float2bfloat16(f);
    return __builtin_bit_cast(unsigned short, h);
}
__device__ __forceinline__ void gld_lds16(const ushort* g, ushort* l) {
    __builtin_amdgcn_global_load_lds((const __attribute__((address_space(1))) void*)g,
                                     (__attribute__((address_space(3))) void*)l,
                                     16, 0, 0);
}

// ---------------- Kernel 1: lower-tri tile pass ----------------
// One block per lower-triangular 64x64 tile (incl. diagonal tiles).
// Reads fp32 tile of A (136 MB total instead of 268), accumulates row sums
// (and, for off-diag tiles, col sums) into acc[b][t] via fp32 atomics
// (symmetry: full rowsum[t] = lower-tri row t + strictly-lower col t),
// and writes the bf16 packed tile (diag tile causally masked).
__global__ __launch_bounds__(256) void tri_pass_kernel(
    const float* __restrict__ A, float* __restrict__ acc, ushort* __restrict__ Apk) {
    __shared__ float tile[64][68];      // stride 68 floats: float4-aligned, 2-way-bank-free
    int bid = blockIdx.x;
    int b = bid / NTRI;
    int r = bid - b * NTRI;
    // triangular index -> (it, kt)
    int it = (int)((sqrtf(8.f * r + 1.f) - 1.f) * 0.5f);
    while ((it + 1) * (it + 2) / 2 <= r) ++it;
    while (it * (it + 1) / 2 > r) --it;
    int kt = r - it * (it + 1) / 2;
    int t0 = it * 64, s0 = kt * 64;
    bool diag = (kt == it);

    int tid = threadIdx.x;
    int i = tid >> 2;                   // row 0..63
    int c0 = (tid & 3) * 16;            // col group

    const float* g = A + ((size_t)(b * Tn + t0 + i) * Tn + s0 + c0);
    float4 v[4];
#pragma unroll
    for (int q = 0; q < 4; ++q) v[q] = *(const float4*)(g + 4 * q);

    float f[16];
#pragma unroll
    for (int q = 0; q < 4; ++q) {
        f[4 * q + 0] = v[q].x; f[4 * q + 1] = v[q].y;
        f[4 * q + 2] = v[q].z; f[4 * q + 3] = v[q].w;
    }
    // row partial (full 64-col row sum; diag tile full row is correct: covers s<t0+64)
    float rp = 0.f;
#pragma unroll
    for (int e = 0; e < 16; ++e) rp += f[e];
    rp += __shfl_xor(rp, 1, 64);
    rp += __shfl_xor(rp, 2, 64);
    if ((tid & 3) == 0) atomicAdd(&acc[b * Tn + t0 + i], rp);

    // stash fp32 for col sums
#pragma unroll
    for (int q = 0; q < 4; ++q) *(float4*)&tile[i][c0 + 4 * q] = v[q];

    // bf16 write (mask diag tile: col > row -> 0)
    ushort* tb = Apk + (size_t)b * NTRI * 4096 + (size_t)(it * (it + 1) / 2 + kt) * 4096;
    unsigned w[8];
#pragma unroll
    for (int e = 0; e < 8; ++e) {
        float lo = f[2 * e], hi = f[2 * e + 1];
        if (diag) {
            if (c0 + 2 * e > i)     lo = 0.f;
            if (c0 + 2 * e + 1 > i) hi = 0.f;
        }
        w[e] = (unsigned)f2bu(lo) | ((unsigned)f2bu(hi) << 16);
    }
    *(uint4*)(tb + i * 64 + c0)     = make_uint4(w[0], w[1], w[2], w[3]);
    *(uint4*)(tb + i * 64 + c0 + 8) = make_uint4(w[4], w[5], w[6], w[7]);

    if (!diag) {
        __syncthreads();
        int j = tid & 63, p = tid >> 6;
        float cp = 0.f;
#pragma unroll
        for (int q = 0; q < 16; ++q) cp += tile[p * 16 + q][j];
        atomicAdd(&acc[b * Tn + s0 + j], cp);
    }
}

// ---------------- Kernel 1b: dis = rsqrt(acc + eps) ----------------
__global__ __launch_bounds__(256) void dis_kernel(const float* __restrict__ acc,
                                                  float* __restrict__ dis) {
    int r = blockIdx.x * 256 + threadIdx.x;
    dis[r] = rsqrtf(acc[r] + 1e-6f);
}

// ---------------- Kernel 2: kT[b][d][s] = bf16(dis[b,s] * k[b][s][d]) ----------------
__global__ __launch_bounds__(256) void scale_transpose_kernel(
    const float* __restrict__ K, const float* __restrict__ dis, ushort* __restrict__ kT) {
    int bid = blockIdx.x;
    int b = bid >> 8;
    int rr = bid & 255;
    int st = rr >> 2, dt = rr & 3;
    int s0 = st * 64, d0 = dt * 64;
    __shared__ ushort tile[64][72];     // padded
    int tid = threadIdx.x;
#pragma unroll
    for (int q = 0; q < 2; ++q) {
        int idx = q * 256 + tid;
        int sl = idx >> 3, dl0 = (idx & 7) * 8;
        const float* g = K + ((size_t)(b * Tn + s0 + sl) * Dn + d0 + dl0);
        float sc = dis[b * Tn + s0 + sl];
        float4 v0 = *(const float4*)g;
        float4 v1 = *(const float4*)(g + 4);
        tile[sl][dl0 + 0] = f2bu(v0.x * sc);
        tile[sl][dl0 + 1] = f2bu(v0.y * sc);
        tile[sl][dl0 + 2] = f2bu(v0.z * sc);
        tile[sl][dl0 + 3] = f2bu(v0.w * sc);
        tile[sl][dl0 + 4] = f2bu(v1.x * sc);
        tile[sl][dl0 + 5] = f2bu(v1.y * sc);
        tile[sl][dl0 + 6] = f2bu(v1.z * sc);
        tile[sl][dl0 + 7] = f2bu(v1.w * sc);
    }
    __syncthreads();
#pragma unroll
    for (int q = 0; q < 2; ++q) {
        int idx = q * 256 + tid;
        int dl = idx >> 3, sl0 = (idx & 7) * 8;
        unsigned w[4];
#pragma unroll
        for (int e = 0; e < 4; ++e) {
            unsigned lo = tile[sl0 + 2 * e][dl];
            unsigned hi = tile[sl0 + 2 * e + 1][dl];
            w[e] = lo | (hi << 16);
        }
        *(uint4*)(kT + ((size_t)(b * Dn + d0 + dl) * Tn + s0 + sl0)) =
            make_uint4(w[0], w[1], w[2], w[3]);
    }
}

// ---------------- Kernel 3: causal MFMA GEMM, double-buffered ----------------
// out[b,t,d] = sqrt(0.5)*dis[t] * sum_{s<=t} Apk[b,t,s] * kT[b,d,s]   (fp32 out)
constexpr int BK = 64;

__global__ __launch_bounds__(256) void gemm_causal_kernel(
    const ushort* __restrict__ Apk, const ushort* __restrict__ kT,
    const float* __restrict__ dis, float* __restrict__ out) {
    __shared__ __attribute__((aligned(16))) ushort As[2][64 * BK];
    __shared__ __attribute__((aligned(16))) ushort Bs[2][64 * BK];
    __shared__ float rs[64];

    int bid = blockIdx.x;
    int it = 63 - (bid >> 4);           // longest-K tiles dispatched first (LPT)
    int sub = bid & 15;
    int b = sub >> 2;
    int d0 = (sub & 3) * 64;
    int t0 = it * 64;

    int tid = threadIdx.x;
    int lane = tid & 63;
    int w = tid >> 6;
    int l15 = lane & 15;
    int kq = (lane >> 4) * 8;

    const ushort* Atri = Apk + (size_t)b * NTRI * 4096 + (size_t)(it * (it + 1) / 2) * 4096;
    const size_t kTbase = (size_t)(b * Dn + d0) * Tn;

    if (tid < 64) rs[tid] = 0.70710678118654752f * dis[b * Tn + t0 + tid];

    f32x4 acc[2][2];
#pragma unroll
    for (int mi = 0; mi < 2; ++mi)
#pragma unroll
        for (int ni = 0; ni < 2; ++ni) acc[mi][ni] = (f32x4){0.f, 0.f, 0.f, 0.f};

    int mrow = (w >> 1) * 32;
    int ncol = (w & 1) * 32;
    int nkt = it + 1;

    auto stage = [&](int buf, int kt) {
#pragma unroll
        for (int q = 0; q < 2; ++q) {
            int idx = q * 256 + tid;
            gld_lds16(Atri + (size_t)kt * 4096 + idx * 8, &As[buf][idx * 8]);
        }
#pragma unroll
        for (int q = 0; q < 2; ++q) {
            int idx = q * 256 + tid;
            int n = idx >> 3, sc = (idx & 7) * 8;
            gld_lds16(kT + kTbase + (size_t)n * Tn + kt * BK + sc, &Bs[buf][idx * 8]);
        }
    };

    stage(0, 0);
    __syncthreads();

    for (int kt = 0; kt < nkt; ++kt) {
        int cur = kt & 1;
        if (kt + 1 < nkt) stage(cur ^ 1, kt + 1);
#pragma unroll
        for (int ki = 0; ki < 2; ++ki) {
            int kc = ki * 32 + kq;
            short8 af[2];
#pragma unroll
            for (int mi = 0; mi < 2; ++mi)
                af[mi] = *(const short8*)&As[cur][(mrow + 16 * mi + l15) * BK + kc];
            short8 bfr[2];
#pragma unroll
            for (int ni = 0; ni < 2; ++ni)
                bfr[ni] = *(const short8*)&Bs[cur][(ncol + 16 * ni + l15) * BK + kc];
#pragma unroll
            for (int mi = 0; mi < 2; ++mi)
#pragma unroll
                for (int ni = 0; ni < 2; ++ni)
                    acc[mi][ni] = __builtin_amdgcn_mfma_f32_16x16x32_bf16(
                        af[mi], bfr[ni], acc[mi][ni], 0, 0, 0);
        }
        __syncthreads();
    }

#pragma unroll
    for (int mi = 0; mi < 2; ++mi) {
#pragma unroll
        for (int ni = 0; ni < 2; ++ni) {
            int tl = mrow + 16 * mi + (lane >> 4) * 4;
            int d = d0 + ncol + 16 * ni + l15;
#pragma unroll
            for (int r = 0; r < 4; ++r) {
                int t = t0 + tl + r;
                out[(size_t)(b * Tn + t) * Dn + d] = acc[mi][ni][r] * rs[tl + r];
            }
        }
    }
}

extern "C" void kernel_launch(void* const* d_in, const int* in_sizes, int n_in,
                              void* d_out, int out_size, void* d_ws, size_t ws_size,
                              hipStream_t stream) {
    const float* A = (const float*)d_in[0];     // A_rel fp32, (4,4096,4096)
    const float* K = (const float*)d_in[1];     // k_seq fp32, (4,4096,256)
    float* out = (float*)d_out;                 // fp32, (4,4096,256)

    float* acc = (float*)d_ws;                          // 16384 f32 = 64 KB
    float* dis = acc + Bn * Tn;                         // 16384 f32 = 64 KB
    ushort* kT = (ushort*)(dis + Bn * Tn);              // 8.39 MB bf16
    ushort* Apk = kT + (size_t)Bn * Dn * Tn;            // 68.2 MB packed-tri bf16

    hipMemsetAsync(acc, 0, Bn * Tn * sizeof(float), stream);
    tri_pass_kernel<<<dim3(Bn * NTRI), dim3(256), 0, stream>>>(A, acc, Apk);
    dis_kernel<<<dim3(Bn * Tn / 256), dim3(256), 0, stream>>>(acc, dis);
    scale_transpose_kernel<<<dim3(Bn * (Tn / 64) * (Dn / 64)), dim3(256), 0, stream>>>(K, dis, kT);
    gemm_causal_kernel<<<dim3(NT * 16), dim3(256), 0, stream>>>(Apk, kT, dis, out);
}

// Round 5
// 399.030 us; speedup vs baseline: 1.1418x; 1.0069x over previous
//
#include <hip/hip_runtime.h>
#include <hip/hip_bf16.h>

// Problem constants (fixed by setup_inputs): fp32 inputs/outputs.
constexpr int Bn = 4;
constexpr int Tn = 4096;
constexpr int Dn = 256;
constexpr int NT = Tn / 64;             // 64 t-tiles per batch
constexpr int NTRI = NT * (NT + 1) / 2; // 2080 lower-tri 64x64 tiles per batch

using ushort = unsigned short;
typedef short short8 __attribute__((ext_vector_type(8)));
typedef float f32x4 __attribute__((ext_vector_type(4)));

__device__ __forceinline__ ushort f2bu(float f) {
    __hip_bfloat16 h = __float2bfloat16(f);
    return __builtin_bit_cast(unsigned short, h);
}
__device__ __forceinline__ void gld_lds16(const ushort* g, ushort* l) {
    __builtin_amdgcn_global_load_lds((const __attribute__((address_space(1))) void*)g,
                                     (__attribute__((address_space(3))) void*)l,
                                     16, 0, 0);
}
__device__ __forceinline__ float dis_of(float a) { return rsqrtf(a + 1e-6f); }

// ---------------- Kernel 1: lower-tri tile pass ----------------
// One block per lower-triangular 64x64 tile. Reads fp32 A tile (136 MB total),
// atomically accumulates row sums (and col sums for off-diag tiles, using
// symmetry) into acc[b][t], writes bf16 packed tile (diag causally masked).
__global__ __launch_bounds__(256) void tri_pass_kernel(
    const float* __restrict__ A, float* __restrict__ acc, ushort* __restrict__ Apk) {
    __shared__ float tile[64][68];      // float4-aligned stride, conflict-benign
    int bid = blockIdx.x;
    int b = bid / NTRI;
    int r = bid - b * NTRI;
    int it = (int)((sqrtf(8.f * r + 1.f) - 1.f) * 0.5f);
    while ((it + 1) * (it + 2) / 2 <= r) ++it;
    while (it * (it + 1) / 2 > r) --it;
    int kt = r - it * (it + 1) / 2;
    int t0 = it * 64, s0 = kt * 64;
    bool diag = (kt == it);

    int tid = threadIdx.x;
    int i = tid >> 2;                   // row 0..63
    int c0 = (tid & 3) * 16;            // col group (16 floats = 64B per thread)

    const float* g = A + ((size_t)(b * Tn + t0 + i) * Tn + s0 + c0);
    float4 v[4];
#pragma unroll
    for (int q = 0; q < 4; ++q) v[q] = *(const float4*)(g + 4 * q);

    float f[16];
#pragma unroll
    for (int q = 0; q < 4; ++q) {
        f[4 * q + 0] = v[q].x; f[4 * q + 1] = v[q].y;
        f[4 * q + 2] = v[q].z; f[4 * q + 3] = v[q].w;
    }
    float rp = 0.f;
#pragma unroll
    for (int e = 0; e < 16; ++e) rp += f[e];
    rp += __shfl_xor(rp, 1, 64);
    rp += __shfl_xor(rp, 2, 64);
    if ((tid & 3) == 0) atomicAdd(&acc[b * Tn + t0 + i], rp);

#pragma unroll
    for (int q = 0; q < 4; ++q) *(float4*)&tile[i][c0 + 4 * q] = v[q];

    ushort* tb = Apk + (size_t)b * NTRI * 4096 + (size_t)(it * (it + 1) / 2 + kt) * 4096;
    unsigned w[8];
#pragma unroll
    for (int e = 0; e < 8; ++e) {
        float lo = f[2 * e], hi = f[2 * e + 1];
        if (diag) {
            if (c0 + 2 * e > i)     lo = 0.f;
            if (c0 + 2 * e + 1 > i) hi = 0.f;
        }
        w[e] = (unsigned)f2bu(lo) | ((unsigned)f2bu(hi) << 16);
    }
    *(uint4*)(tb + i * 64 + c0)     = make_uint4(w[0], w[1], w[2], w[3]);
    *(uint4*)(tb + i * 64 + c0 + 8) = make_uint4(w[4], w[5], w[6], w[7]);

    if (!diag) {
        __syncthreads();
        int j = tid & 63, p = tid >> 6;
        float cp = 0.f;
#pragma unroll
        for (int q = 0; q < 16; ++q) cp += tile[p * 16 + q][j];
        atomicAdd(&acc[b * Tn + s0 + j], cp);
    }
}

// ---------------- Kernel 2: kT[b][d][s] = bf16(dis(acc[b,s]) * k[b][s][d]) ----------------
__global__ __launch_bounds__(256) void scale_transpose_kernel(
    const float* __restrict__ K, const float* __restrict__ acc, ushort* __restrict__ kT) {
    int bid = blockIdx.x;
    int b = bid >> 8;
    int rr = bid & 255;
    int st = rr >> 2, dt = rr & 3;
    int s0 = st * 64, d0 = dt * 64;
    __shared__ ushort tile[64][72];     // padded
    int tid = threadIdx.x;
#pragma unroll
    for (int q = 0; q < 2; ++q) {
        int idx = q * 256 + tid;
        int sl = idx >> 3, dl0 = (idx & 7) * 8;
        const float* g = K + ((size_t)(b * Tn + s0 + sl) * Dn + d0 + dl0);
        float sc = dis_of(acc[b * Tn + s0 + sl]);
        float4 v0 = *(const float4*)g;
        float4 v1 = *(const float4*)(g + 4);
        tile[sl][dl0 + 0] = f2bu(v0.x * sc);
        tile[sl][dl0 + 1] = f2bu(v0.y * sc);
        tile[sl][dl0 + 2] = f2bu(v0.z * sc);
        tile[sl][dl0 + 3] = f2bu(v0.w * sc);
        tile[sl][dl0 + 4] = f2bu(v1.x * sc);
        tile[sl][dl0 + 5] = f2bu(v1.y * sc);
        tile[sl][dl0 + 6] = f2bu(v1.z * sc);
        tile[sl][dl0 + 7] = f2bu(v1.w * sc);
    }
    __syncthreads();
#pragma unroll
    for (int q = 0; q < 2; ++q) {
        int idx = q * 256 + tid;
        int dl = idx >> 3, sl0 = (idx & 7) * 8;
        unsigned w[4];
#pragma unroll
        for (int e = 0; e < 4; ++e) {
            unsigned lo = tile[sl0 + 2 * e][dl];
            unsigned hi = tile[sl0 + 2 * e + 1][dl];
            w[e] = lo | (hi << 16);
        }
        *(uint4*)(kT + ((size_t)(b * Dn + d0 + dl) * Tn + s0 + sl0)) =
            make_uint4(w[0], w[1], w[2], w[3]);
    }
}

// ---------------- Kernel 3: causal MFMA GEMM, double-buffered ----------------
// out[b,t,d] = sqrt(0.5)*dis(acc[t]) * sum_{s<=t} Apk[b,t,s] * kT[b,d,s]  (fp32 out)
constexpr int BK = 64;

__global__ __launch_bounds__(256) void gemm_causal_kernel(
    const ushort* __restrict__ Apk, const ushort* __restrict__ kT,
    const float* __restrict__ acc_in, float* __restrict__ out) {
    __shared__ __attribute__((aligned(16))) ushort As[2][64 * BK];
    __shared__ __attribute__((aligned(16))) ushort Bs[2][64 * BK];
    __shared__ float rs[64];

    int bid = blockIdx.x;
    int it = 63 - (bid >> 4);           // longest-K tiles dispatched first (LPT)
    int sub = bid & 15;
    int b = sub >> 2;
    int d0 = (sub & 3) * 64;
    int t0 = it * 64;

    int tid = threadIdx.x;
    int lane = tid & 63;
    int w = tid >> 6;
    int l15 = lane & 15;
    int kq = (lane >> 4) * 8;

    const ushort* Atri = Apk + (size_t)b * NTRI * 4096 + (size_t)(it * (it + 1) / 2) * 4096;
    const size_t kTbase = (size_t)(b * Dn + d0) * Tn;

    if (tid < 64) rs[tid] = 0.70710678118654752f * dis_of(acc_in[b * Tn + t0 + tid]);

    f32x4 acc[2][2];
#pragma unroll
    for (int mi = 0; mi < 2; ++mi)
#pragma unroll
        for (int ni = 0; ni < 2; ++ni) acc[mi][ni] = (f32x4){0.f, 0.f, 0.f, 0.f};

    int mrow = (w >> 1) * 32;
    int ncol = (w & 1) * 32;
    int nkt = it + 1;

    auto stage = [&](int buf, int kt) {
#pragma unroll
        for (int q = 0; q < 2; ++q) {
            int idx = q * 256 + tid;
            gld_lds16(Atri + (size_t)kt * 4096 + idx * 8, &As[buf][idx * 8]);
        }
#pragma unroll
        for (int q = 0; q < 2; ++q) {
            int idx = q * 256 + tid;
            int n = idx >> 3, sc = (idx & 7) * 8;
            gld_lds16(kT + kTbase + (size_t)n * Tn + kt * BK + sc, &Bs[buf][idx * 8]);
        }
    };

    stage(0, 0);
    __syncthreads();

    for (int kt = 0; kt < nkt; ++kt) {
        int cur = kt & 1;
        if (kt + 1 < nkt) stage(cur ^ 1, kt + 1);
#pragma unroll
        for (int ki = 0; ki < 2; ++ki) {
            int kc = ki * 32 + kq;
            short8 af[2];
#pragma unroll
            for (int mi = 0; mi < 2; ++mi)
                af[mi] = *(const short8*)&As[cur][(mrow + 16 * mi + l15) * BK + kc];
            short8 bfr[2];
#pragma unroll
            for (int ni = 0; ni < 2; ++ni)
                bfr[ni] = *(const short8*)&Bs[cur][(ncol + 16 * ni + l15) * BK + kc];
#pragma unroll
            for (int mi = 0; mi < 2; ++mi)
#pragma unroll
                for (int ni = 0; ni < 2; ++ni)
                    acc[mi][ni] = __builtin_amdgcn_mfma_f32_16x16x32_bf16(
                        af[mi], bfr[ni], acc[mi][ni], 0, 0, 0);
        }
        __syncthreads();
    }

#pragma unroll
    for (int mi = 0; mi < 2; ++mi) {
#pragma unroll
        for (int ni = 0; ni < 2; ++ni) {
            int tl = mrow + 16 * mi + (lane >> 4) * 4;
            int d = d0 + ncol + 16 * ni + l15;
#pragma unroll
            for (int r = 0; r < 4; ++r) {
                int t = t0 + tl + r;
                out[(size_t)(b * Tn + t) * Dn + d] = acc[mi][ni][r] * rs[tl + r];
            }
        }
    }
}

extern "C" void kernel_launch(void* const* d_in, const int* in_sizes, int n_in,
                              void* d_out, int out_size, void* d_ws, size_t ws_size,
                              hipStream_t stream) {
    const float* A = (const float*)d_in[0];     // A_rel fp32, (4,4096,4096)
    const float* K = (const float*)d_in[1];     // k_seq fp32, (4,4096,256)
    float* out = (float*)d_out;                 // fp32, (4,4096,256)

    float* acc = (float*)d_ws;                          // 16384 f32 = 64 KB
    ushort* kT = (ushort*)(acc + Bn * Tn);              // 8.39 MB bf16
    ushort* Apk = kT + (size_t)Bn * Dn * Tn;            // 68.2 MB packed-tri bf16

    hipMemsetAsync(acc, 0, Bn * Tn * sizeof(float), stream);
    tri_pass_kernel<<<dim3(Bn * NTRI), dim3(256), 0, stream>>>(A, acc, Apk);
    scale_transpose_kernel<<<dim3(Bn * (Tn / 64) * (Dn / 64)), dim3(256), 0, stream>>>(K, acc, kT);
    gemm_causal_kernel<<<dim3(NT * 16), dim3(256), 0, stream>>>(Apk, kT, acc, out);
}